// Round 7
// baseline (315.126 us; speedup 1.0000x reference)
//
#include <hip/hip_runtime.h>
#include <hip/hip_bf16.h>

#define N_NODES 100000
#define N_EDGES 1600000
#define NFEAT 256
#define NHID 128
#define NCLASS 8

#define NBLK 512                       // pass-A blocks
#define BSH 8                          // bucket = dst >> 8 (256 nodes/bucket)
#define BUCK 256
#define NBUCK ((N_NODES + BUCK - 1) / BUCK)   // 391

// ---------------------------------------------------------------------------
// A1: per-block coarse histogram (391 buckets) via LDS atomics.
__global__ __launch_bounds__(256) void hist_kernel(const int* __restrict__ edst,
                                                   int* __restrict__ blockhist,
                                                   int chunk, int nE) {
    __shared__ int h[NBUCK];
    int tid = threadIdx.x;
    for (int i = tid; i < NBUCK; i += 256) h[i] = 0;
    __syncthreads();
    int e0 = blockIdx.x * chunk;
    int e1 = min(e0 + chunk, nE);
    for (int e = e0 + tid; e < e1; e += 256)
        atomicAdd(&h[edst[e] >> BSH], 1);            // LDS atomic
    __syncthreads();
    for (int i = tid; i < NBUCK; i += 256)
        blockhist[(long)blockIdx.x * NBUCK + i] = h[i];
}

// ---------------------------------------------------------------------------
// A2: per-bucket exclusive scan over the 512 per-block counts.
__global__ __launch_bounds__(256) void scanblk_kernel(const int* __restrict__ blockhist,
                                                      int* __restrict__ blockbase,
                                                      int* __restrict__ bucket_total) {
    __shared__ int ss[256];
    int b = blockIdx.x, tid = threadIdx.x;
    int v0 = blockhist[(long)tid * NBUCK + b];
    int v1 = blockhist[(long)(tid + 256) * NBUCK + b];
    int t = v0 + v1;
    ss[tid] = t; __syncthreads();
    for (int o = 1; o < 256; o <<= 1) {
        int u = (tid >= o) ? ss[tid - o] : 0;
        __syncthreads(); ss[tid] += u; __syncthreads();
    }
    int ex = ss[tid] - t;
    blockbase[(long)tid * NBUCK + b] = ex;
    blockbase[(long)(tid + 256) * NBUCK + b] = ex + v0;
    if (tid == 255) bucket_total[b] = ss[255];
}

// ---------------------------------------------------------------------------
// Mid: block 0 = exclusive scan over bucket totals; block 1 = Wc/cvec precompute.
__global__ __launch_bounds__(512) void mid_kernel(const int* __restrict__ bucket_total,
                                                  int* __restrict__ bucket_base,
                                                  const float* __restrict__ W1,
                                                  const float* __restrict__ b1,
                                                  const float* __restrict__ Wfc,
                                                  const float* __restrict__ bfc,
                                                  float* __restrict__ WcT,
                                                  float* __restrict__ cvec) {
    int tid = threadIdx.x;
    if (blockIdx.x == 0) {
        __shared__ int ss[512];
        int v = (tid < NBUCK) ? bucket_total[tid] : 0;
        ss[tid] = v; __syncthreads();
        for (int o = 1; o < 512; o <<= 1) {
            int u = (tid >= o) ? ss[tid - o] : 0;
            __syncthreads(); ss[tid] += u; __syncthreads();
        }
        if (tid < NBUCK) bucket_base[tid] = ss[tid] - v;
        if (tid == NBUCK - 1) bucket_base[NBUCK] = ss[tid];
    } else {
        __shared__ float wfs[NHID * NCLASS];
        __shared__ float bs[NHID];
        for (int i = tid; i < NHID * NCLASS; i += 512) wfs[i] = Wfc[i];
        if (tid < NHID) bs[tid] = b1[tid];
        __syncthreads();
        if (tid < NFEAT) {
            float acc[NCLASS] = {};
            for (int h = 0; h < NHID; h++) {
                float w = W1[tid * NHID + h];
                #pragma unroll
                for (int c = 0; c < NCLASS; c++) acc[c] += w * wfs[h * NCLASS + c];
            }
            #pragma unroll
            for (int c = 0; c < NCLASS; c++) WcT[c * NFEAT + tid] = acc[c];
        }
        if (tid < NCLASS) {
            float a = bfc[tid];
            for (int h = 0; h < NHID; h++) a += bs[h] * wfs[h * NCLASS + tid];
            cvec[tid] = a;
        }
    }
}

// ---------------------------------------------------------------------------
// A3: scatter packed (src<<8 | local_dst) into bucket-grouped ebufP (4 B/edge).
__global__ __launch_bounds__(256) void scat_kernel(const int* __restrict__ esrc,
                                                   const int* __restrict__ edst,
                                                   const int* __restrict__ blockbase,
                                                   const int* __restrict__ bucket_base,
                                                   int* __restrict__ ebufP,
                                                   int chunk, int nE) {
    __shared__ int cur[NBUCK];
    int tid = threadIdx.x;
    for (int i = tid; i < NBUCK; i += 256)
        cur[i] = bucket_base[i] + blockbase[(long)blockIdx.x * NBUCK + i];
    __syncthreads();
    int e0 = blockIdx.x * chunk;
    int e1 = min(e0 + chunk, nE);
    for (int e = e0 + tid; e < e1; e += 256) {
        int s = esrc[e];
        int d = edst[e];
        int pos = atomicAdd(&cur[d >> BSH], 1);      // LDS atomic
        ebufP[pos] = (s << BSH) | (d & (BUCK - 1));
    }
}

// ---------------------------------------------------------------------------
// B-lite: exact per-node degree per bucket (LDS counters) -> dinv. No placement.
__global__ __launch_bounds__(256) void deg_dinv_kernel(const int* __restrict__ ebufP,
                                                       const int* __restrict__ bucket_base,
                                                       float* __restrict__ dinv) {
    __shared__ int cnt[BUCK];
    int b = blockIdx.x, tid = threadIdx.x;
    cnt[tid] = 0;
    __syncthreads();
    int base = bucket_base[b], end = bucket_base[b + 1];
    for (int e = base + tid; e < end; e += 256)
        atomicAdd(&cnt[ebufP[e] & (BUCK - 1)], 1);   // LDS atomic
    __syncthreads();
    int node = (b << BSH) + tid;
    if (node < N_NODES) dinv[node] = rsqrtf((float)(cnt[tid] + 1));
}

// ---------------------------------------------------------------------------
// Kz: Zs[i][c] = dot(X[i], WcT[c]) * dinv[i].  Wave = 8 rows; 8 lanes/row
// own 32 features in 8 float4 regs; WcT in LDS; shfl_xor reduce per class.
__global__ __launch_bounds__(256) void z_kernel(const float* __restrict__ X,
                                                const float* __restrict__ WcT,
                                                const float* __restrict__ dinv,
                                                float* __restrict__ Zs, int n) {
    __shared__ float4 wlds[NCLASS * 64];
    int tid = threadIdx.x;
    #pragma unroll
    for (int i = tid; i < NCLASS * 64; i += 256)
        wlds[i] = ((const float4*)WcT)[i];
    __syncthreads();

    const int lane = tid & 63;
    const int sub  = lane & 7;
    const int rsub = lane >> 3;
    const int wid  = (blockIdx.x * 256 + tid) >> 6;
    const int nw   = (gridDim.x * 256) >> 6;
    const int ngroups = (n + 7) >> 3;

    for (int g = wid; g < ngroups; g += nw) {
        int row = g * 8 + rsub;
        bool ok = row < n;
        int r = ok ? row : (n - 1);
        const float4* xr = (const float4*)(X + (long)r * NFEAT);
        float4 xv[8];
        #pragma unroll
        for (int k = 0; k < 8; k++) xv[k] = xr[sub + 8 * k];

        float res = 0.f;
        #pragma unroll
        for (int c = 0; c < NCLASS; c++) {
            float s = 0.f;
            #pragma unroll
            for (int k = 0; k < 8; k++) {
                float4 w = wlds[c * 64 + sub + 8 * k];
                s += xv[k].x * w.x + xv[k].y * w.y + xv[k].z * w.z + xv[k].w * w.w;
            }
            s += __shfl_xor(s, 1);
            s += __shfl_xor(s, 2);
            s += __shfl_xor(s, 4);
            if (sub == c) res = s;
        }
        if (ok) Zs[(long)row * NCLASS + sub] = res * dinv[row];
    }
}

// ---------------------------------------------------------------------------
// Kg: block per bucket. Accumulate all edges into LDS acc[c][li] via float
// LDS atomics, then out[node] = dinv*(Zs[node] + acc) + cvec.
__global__ __launch_bounds__(512) void bucket_gather_kernel(
        const float* __restrict__ Zs,
        const int* __restrict__ ebufP,
        const int* __restrict__ bucket_base,
        const float* __restrict__ dinv,
        const float* __restrict__ cvec,
        float* __restrict__ out, int n) {
    __shared__ float acc[NCLASS * BUCK];   // acc[c*256 + li], 8 KB
    int b = blockIdx.x, tid = threadIdx.x;
    for (int i = tid; i < NCLASS * BUCK; i += 512) acc[i] = 0.f;
    __syncthreads();

    int base = bucket_base[b], end = bucket_base[b + 1];
    const float4* Zs4 = (const float4*)Zs;

    for (int e = base + tid; e < end; e += 512) {
        int p   = ebufP[e];
        int src = p >> BSH;
        int li  = p & (BUCK - 1);
        float4 z0 = Zs4[src * 2];
        float4 z1 = Zs4[src * 2 + 1];
        atomicAdd(&acc[0 * BUCK + li], z0.x);
        atomicAdd(&acc[1 * BUCK + li], z0.y);
        atomicAdd(&acc[2 * BUCK + li], z0.z);
        atomicAdd(&acc[3 * BUCK + li], z0.w);
        atomicAdd(&acc[4 * BUCK + li], z1.x);
        atomicAdd(&acc[5 * BUCK + li], z1.y);
        atomicAdd(&acc[6 * BUCK + li], z1.z);
        atomicAdd(&acc[7 * BUCK + li], z1.w);
    }
    __syncthreads();

    if (tid < BUCK) {
        int node = (b << BSH) + tid;
        if (node < n) {
            float4 s0 = Zs4[node * 2];
            float4 s1 = Zs4[node * 2 + 1];
            float dd = dinv[node];
            float4 c0 = ((const float4*)cvec)[0];
            float4 c1 = ((const float4*)cvec)[1];
            float4 o0, o1;
            o0.x = (s0.x + acc[0 * BUCK + tid]) * dd + c0.x;
            o0.y = (s0.y + acc[1 * BUCK + tid]) * dd + c0.y;
            o0.z = (s0.z + acc[2 * BUCK + tid]) * dd + c0.z;
            o0.w = (s0.w + acc[3 * BUCK + tid]) * dd + c0.w;
            o1.x = (s1.x + acc[4 * BUCK + tid]) * dd + c1.x;
            o1.y = (s1.y + acc[5 * BUCK + tid]) * dd + c1.y;
            o1.z = (s1.z + acc[6 * BUCK + tid]) * dd + c1.z;
            o1.w = (s1.w + acc[7 * BUCK + tid]) * dd + c1.w;
            ((float4*)out)[node * 2]     = o0;
            ((float4*)out)[node * 2 + 1] = o1;
        }
    }
}

// ---------------------------------------------------------------------------
extern "C" void kernel_launch(void* const* d_in, const int* in_sizes, int n_in,
                              void* d_out, int out_size, void* d_ws, size_t ws_size,
                              hipStream_t stream) {
    const float* x    = (const float*)d_in[0];   // [N, 256]
    const int*   eidx = (const int*)d_in[1];     // [2, E]
    const float* W1   = (const float*)d_in[2];   // [256, 128]
    const float* b1   = (const float*)d_in[3];   // [128]
    const float* Wfc  = (const float*)d_in[4];   // [128, 8]
    const float* bfc  = (const float*)d_in[5];   // [8]
    float* out = (float*)d_out;

    const int N = N_NODES;
    const int E = in_sizes[1] / 2;
    const int chunk = (E + NBLK - 1) / NBLK;

    const int* esrc = eidx;
    const int* edst = eidx + E;

    // workspace layout (~12 MB); every region written before read, no memsets.
    float* Zs    = (float*)d_ws;                     // 8N   (16B-aligned)
    float* dinv  = Zs + (long)8 * N;                 // N
    float* cvec  = dinv + N;                         // 8    (16B-aligned)
    float* WcT   = cvec + 8;                         // 2048
    int*   btot  = (int*)(WcT + NCLASS * NFEAT);     // NBUCK (padded)
    int*   bbase = btot + NBUCK + 1;                 // NBUCK+1 (padded)
    int*   bhist = bbase + NBUCK + 3;                // NBLK*NBUCK
    int*   bbas2 = bhist + (long)NBLK * NBUCK;       // NBLK*NBUCK
    int*   ebufP = bbas2 + (long)NBLK * NBUCK;       // E

    hist_kernel<<<NBLK, 256, 0, stream>>>(edst, bhist, chunk, E);
    scanblk_kernel<<<NBUCK, 256, 0, stream>>>(bhist, bbas2, btot);
    mid_kernel<<<2, 512, 0, stream>>>(btot, bbase, W1, b1, Wfc, bfc, WcT, cvec);
    scat_kernel<<<NBLK, 256, 0, stream>>>(esrc, edst, bbas2, bbase, ebufP, chunk, E);
    deg_dinv_kernel<<<NBUCK, 256, 0, stream>>>(ebufP, bbase, dinv);
    z_kernel<<<1563, 256, 0, stream>>>(x, WcT, dinv, Zs, N);
    bucket_gather_kernel<<<NBUCK, 512, 0, stream>>>(Zs, ebufP, bbase, dinv, cvec, out, N);
}

// Round 8
// 242.994 us; speedup vs baseline: 1.2968x; 1.2968x over previous
//
#include <hip/hip_runtime.h>
#include <hip/hip_bf16.h>

#define N_NODES 100000
#define N_EDGES 1600000
#define NFEAT 256
#define NHID 128
#define NCLASS 8

#define NBLK 512                       // pass-A blocks
#define BSH 8                          // bucket = dst >> 8 (256 nodes/bucket)
#define BUCK 256
#define NBUCK ((N_NODES + BUCK - 1) / BUCK)   // 391
#define CAPE 6144                      // LDS edge capacity (mean 4096, sigma 64)

// ---------------------------------------------------------------------------
// A1: per-block coarse histogram (391 buckets) via LDS atomics.
__global__ __launch_bounds__(256) void hist_kernel(const int* __restrict__ edst,
                                                   int* __restrict__ blockhist,
                                                   int chunk, int nE) {
    __shared__ int h[NBUCK];
    int tid = threadIdx.x;
    for (int i = tid; i < NBUCK; i += 256) h[i] = 0;
    __syncthreads();
    int e0 = blockIdx.x * chunk;
    int e1 = min(e0 + chunk, nE);
    for (int e = e0 + tid; e < e1; e += 256)
        atomicAdd(&h[edst[e] >> BSH], 1);            // LDS atomic
    __syncthreads();
    for (int i = tid; i < NBUCK; i += 256)
        blockhist[(long)blockIdx.x * NBUCK + i] = h[i];
}

// ---------------------------------------------------------------------------
// A2: per-bucket exclusive scan over the 512 per-block counts.
__global__ __launch_bounds__(256) void scanblk_kernel(const int* __restrict__ blockhist,
                                                      int* __restrict__ blockbase,
                                                      int* __restrict__ bucket_total) {
    __shared__ int ss[256];
    int b = blockIdx.x, tid = threadIdx.x;
    int v0 = blockhist[(long)tid * NBUCK + b];
    int v1 = blockhist[(long)(tid + 256) * NBUCK + b];
    int t = v0 + v1;
    ss[tid] = t; __syncthreads();
    for (int o = 1; o < 256; o <<= 1) {
        int u = (tid >= o) ? ss[tid - o] : 0;
        __syncthreads(); ss[tid] += u; __syncthreads();
    }
    int ex = ss[tid] - t;
    blockbase[(long)tid * NBUCK + b] = ex;
    blockbase[(long)(tid + 256) * NBUCK + b] = ex + v0;
    if (tid == 255) bucket_total[b] = ss[255];
}

// ---------------------------------------------------------------------------
// Mid: block 0 = exclusive scan over bucket totals; block 1 = Wc/cvec precompute.
__global__ __launch_bounds__(512) void mid_kernel(const int* __restrict__ bucket_total,
                                                  int* __restrict__ bucket_base,
                                                  const float* __restrict__ W1,
                                                  const float* __restrict__ b1,
                                                  const float* __restrict__ Wfc,
                                                  const float* __restrict__ bfc,
                                                  float* __restrict__ WcT,
                                                  float* __restrict__ cvec) {
    int tid = threadIdx.x;
    if (blockIdx.x == 0) {
        __shared__ int ss[512];
        int v = (tid < NBUCK) ? bucket_total[tid] : 0;
        ss[tid] = v; __syncthreads();
        for (int o = 1; o < 512; o <<= 1) {
            int u = (tid >= o) ? ss[tid - o] : 0;
            __syncthreads(); ss[tid] += u; __syncthreads();
        }
        if (tid < NBUCK) bucket_base[tid] = ss[tid] - v;
        if (tid == NBUCK - 1) bucket_base[NBUCK] = ss[tid];
    } else {
        __shared__ float wfs[NHID * NCLASS];
        __shared__ float bs[NHID];
        for (int i = tid; i < NHID * NCLASS; i += 512) wfs[i] = Wfc[i];
        if (tid < NHID) bs[tid] = b1[tid];
        __syncthreads();
        if (tid < NFEAT) {
            float acc[NCLASS] = {};
            for (int h = 0; h < NHID; h++) {
                float w = W1[tid * NHID + h];
                #pragma unroll
                for (int c = 0; c < NCLASS; c++) acc[c] += w * wfs[h * NCLASS + c];
            }
            #pragma unroll
            for (int c = 0; c < NCLASS; c++) WcT[c * NFEAT + tid] = acc[c];
        }
        if (tid < NCLASS) {
            float a = bfc[tid];
            for (int h = 0; h < NHID; h++) a += bs[h] * wfs[h * NCLASS + tid];
            cvec[tid] = a;
        }
    }
}

// ---------------------------------------------------------------------------
// A3: scatter packed (src<<8 | local_dst) into bucket-grouped ebufP (4 B/edge).
__global__ __launch_bounds__(256) void scat_kernel(const int* __restrict__ esrc,
                                                   const int* __restrict__ edst,
                                                   const int* __restrict__ blockbase,
                                                   const int* __restrict__ bucket_base,
                                                   int* __restrict__ ebufP,
                                                   int chunk, int nE) {
    __shared__ int cur[NBUCK];
    int tid = threadIdx.x;
    for (int i = tid; i < NBUCK; i += 256)
        cur[i] = bucket_base[i] + blockbase[(long)blockIdx.x * NBUCK + i];
    __syncthreads();
    int e0 = blockIdx.x * chunk;
    int e1 = min(e0 + chunk, nE);
    for (int e = e0 + tid; e < e1; e += 256) {
        int s = esrc[e];
        int d = edst[e];
        int pos = atomicAdd(&cur[d >> BSH], 1);      // LDS atomic
        ebufP[pos] = (s << BSH) | (d & (BUCK - 1));
    }
}

// ---------------------------------------------------------------------------
// B-lite: exact per-node degree per bucket (LDS counters) -> dinv.
__global__ __launch_bounds__(256) void deg_dinv_kernel(const int* __restrict__ ebufP,
                                                       const int* __restrict__ bucket_base,
                                                       float* __restrict__ dinv) {
    __shared__ int cnt[BUCK];
    int b = blockIdx.x, tid = threadIdx.x;
    cnt[tid] = 0;
    __syncthreads();
    int base = bucket_base[b], end = bucket_base[b + 1];
    for (int e = base + tid; e < end; e += 256)
        atomicAdd(&cnt[ebufP[e] & (BUCK - 1)], 1);   // LDS atomic
    __syncthreads();
    int node = (b << BSH) + tid;
    if (node < N_NODES) dinv[node] = rsqrtf((float)(cnt[tid] + 1));
}

// ---------------------------------------------------------------------------
// Kz: Zs[i][c] = dot(X[i], WcT[c]) * dinv[i].  Wave = 8 rows; 8 lanes/row
// own 32 features in 8 float4 regs; WcT in LDS; shfl_xor reduce per class.
__global__ __launch_bounds__(256) void z_kernel(const float* __restrict__ X,
                                                const float* __restrict__ WcT,
                                                const float* __restrict__ dinv,
                                                float* __restrict__ Zs, int n) {
    __shared__ float4 wlds[NCLASS * 64];
    int tid = threadIdx.x;
    #pragma unroll
    for (int i = tid; i < NCLASS * 64; i += 256)
        wlds[i] = ((const float4*)WcT)[i];
    __syncthreads();

    const int lane = tid & 63;
    const int sub  = lane & 7;
    const int rsub = lane >> 3;
    const int wid  = (blockIdx.x * 256 + tid) >> 6;
    const int nw   = (gridDim.x * 256) >> 6;
    const int ngroups = (n + 7) >> 3;

    for (int g = wid; g < ngroups; g += nw) {
        int row = g * 8 + rsub;
        bool ok = row < n;
        int r = ok ? row : (n - 1);
        const float4* xr = (const float4*)(X + (long)r * NFEAT);
        float4 xv[8];
        #pragma unroll
        for (int k = 0; k < 8; k++) xv[k] = xr[sub + 8 * k];

        float res = 0.f;
        #pragma unroll
        for (int c = 0; c < NCLASS; c++) {
            float s = 0.f;
            #pragma unroll
            for (int k = 0; k < 8; k++) {
                float4 w = wlds[c * 64 + sub + 8 * k];
                s += xv[k].x * w.x + xv[k].y * w.y + xv[k].z * w.z + xv[k].w * w.w;
            }
            s += __shfl_xor(s, 1);
            s += __shfl_xor(s, 2);
            s += __shfl_xor(s, 4);
            if (sub == c) res = s;
        }
        if (ok) Zs[(long)row * NCLASS + sub] = res * dinv[row];
    }
}

// ---------------------------------------------------------------------------
// Kg: fused in-LDS counting sort + register-accumulate gather.
// Block per 256-node bucket, 512 threads.
//   pass1: per-node count (1 LDS int atomic per edge)
//   scan : 256-wide exclusive scan -> off[]
//   pass2: place src into sorted[] (1 LDS write per edge)
//   pass3: thread-per-(node,half) walks its segment, float4 Zs loads, regs.
// Fallback (bucket > CAPE edges — never in practice): LDS float-atomic path.
__global__ __launch_bounds__(512) void sort_gather_kernel(
        const float* __restrict__ Zs,
        const int* __restrict__ ebufP,
        const int* __restrict__ bucket_base,
        const float* __restrict__ dinv,
        const float* __restrict__ cvec,
        float* __restrict__ out, int n) {
    __shared__ int cnt[BUCK];          // counts, then cursors
    __shared__ int off[BUCK + 1];
    __shared__ int ss[BUCK];
    __shared__ int sorted[CAPE];       // fallback reuses as float acc[2048]
    int b = blockIdx.x, tid = threadIdx.x;
    int base = bucket_base[b], end = bucket_base[b + 1];
    int total = end - base;
    const float4* Zs4 = (const float4*)Zs;
    float4 c0v = ((const float4*)cvec)[0];
    float4 c1v = ((const float4*)cvec)[1];

    if (total <= CAPE) {
        if (tid < BUCK) cnt[tid] = 0;
        __syncthreads();
        for (int e = base + tid; e < end; e += 512)
            atomicAdd(&cnt[ebufP[e] & (BUCK - 1)], 1);        // LDS atomic
        __syncthreads();

        int t = (tid < BUCK) ? cnt[tid] : 0;
        if (tid < BUCK) ss[tid] = t;
        __syncthreads();
        for (int o = 1; o < BUCK; o <<= 1) {
            int u = 0;
            if (tid < BUCK && tid >= o) u = ss[tid - o];
            __syncthreads();
            if (tid < BUCK) ss[tid] += u;
            __syncthreads();
        }
        if (tid < BUCK) {
            off[tid] = ss[tid] - t;
            cnt[tid] = ss[tid] - t;     // cursor
            if (tid == BUCK - 1) off[BUCK] = ss[tid];
        }
        __syncthreads();

        for (int e = base + tid; e < end; e += 512) {
            int p = ebufP[e];
            int slot = atomicAdd(&cnt[p & (BUCK - 1)], 1);    // LDS atomic
            sorted[slot] = p >> BSH;
        }
        __syncthreads();

        int li = tid >> 1;
        int h  = tid & 1;
        int node = (b << BSH) + li;
        if (node < n) {
            int k0 = off[li], k1 = off[li + 1];
            float4 a = Zs4[node * 2 + h];                     // self-loop
            int k = k0;
            for (; k + 1 < k1; k += 2) {
                int s0 = sorted[k], s1 = sorted[k + 1];
                float4 z0 = Zs4[s0 * 2 + h];
                float4 z1 = Zs4[s1 * 2 + h];
                a.x += z0.x + z1.x; a.y += z0.y + z1.y;
                a.z += z0.z + z1.z; a.w += z0.w + z1.w;
            }
            if (k < k1) {
                float4 z = Zs4[sorted[k] * 2 + h];
                a.x += z.x; a.y += z.y; a.z += z.z; a.w += z.w;
            }
            float dd = dinv[node];
            float4 cv = h ? c1v : c0v;
            float4 o;
            o.x = a.x * dd + cv.x; o.y = a.y * dd + cv.y;
            o.z = a.z * dd + cv.z; o.w = a.w * dd + cv.w;
            ((float4*)out)[node * 2 + h] = o;
        }
    } else {
        // fallback: LDS float-atomic accumulation (never taken in practice)
        float* acc = (float*)sorted;   // 2048 floats
        for (int i = tid; i < NCLASS * BUCK; i += 512) acc[i] = 0.f;
        __syncthreads();
        for (int e = base + tid; e < end; e += 512) {
            int p = ebufP[e];
            int src = p >> BSH;
            int li = p & (BUCK - 1);
            float4 z0 = Zs4[src * 2];
            float4 z1 = Zs4[src * 2 + 1];
            atomicAdd(&acc[0 * BUCK + li], z0.x);
            atomicAdd(&acc[1 * BUCK + li], z0.y);
            atomicAdd(&acc[2 * BUCK + li], z0.z);
            atomicAdd(&acc[3 * BUCK + li], z0.w);
            atomicAdd(&acc[4 * BUCK + li], z1.x);
            atomicAdd(&acc[5 * BUCK + li], z1.y);
            atomicAdd(&acc[6 * BUCK + li], z1.z);
            atomicAdd(&acc[7 * BUCK + li], z1.w);
        }
        __syncthreads();
        if (tid < BUCK) {
            int node = (b << BSH) + tid;
            if (node < n) {
                float4 s0 = Zs4[node * 2];
                float4 s1 = Zs4[node * 2 + 1];
                float dd = dinv[node];
                float4 o0, o1;
                o0.x = (s0.x + acc[0 * BUCK + tid]) * dd + c0v.x;
                o0.y = (s0.y + acc[1 * BUCK + tid]) * dd + c0v.y;
                o0.z = (s0.z + acc[2 * BUCK + tid]) * dd + c0v.z;
                o0.w = (s0.w + acc[3 * BUCK + tid]) * dd + c0v.w;
                o1.x = (s1.x + acc[4 * BUCK + tid]) * dd + c1v.x;
                o1.y = (s1.y + acc[5 * BUCK + tid]) * dd + c1v.y;
                o1.z = (s1.z + acc[6 * BUCK + tid]) * dd + c1v.z;
                o1.w = (s1.w + acc[7 * BUCK + tid]) * dd + c1v.w;
                ((float4*)out)[node * 2]     = o0;
                ((float4*)out)[node * 2 + 1] = o1;
            }
        }
    }
}

// ---------------------------------------------------------------------------
extern "C" void kernel_launch(void* const* d_in, const int* in_sizes, int n_in,
                              void* d_out, int out_size, void* d_ws, size_t ws_size,
                              hipStream_t stream) {
    const float* x    = (const float*)d_in[0];   // [N, 256]
    const int*   eidx = (const int*)d_in[1];     // [2, E]
    const float* W1   = (const float*)d_in[2];   // [256, 128]
    const float* b1   = (const float*)d_in[3];   // [128]
    const float* Wfc  = (const float*)d_in[4];   // [128, 8]
    const float* bfc  = (const float*)d_in[5];   // [8]
    float* out = (float*)d_out;

    const int N = N_NODES;
    const int E = in_sizes[1] / 2;
    const int chunk = (E + NBLK - 1) / NBLK;

    const int* esrc = eidx;
    const int* edst = eidx + E;

    // workspace layout (~12 MB); every region written before read, no memsets.
    float* Zs    = (float*)d_ws;                     // 8N   (16B-aligned)
    float* dinv  = Zs + (long)8 * N;                 // N
    float* cvec  = dinv + N;                         // 8    (16B-aligned)
    float* WcT   = cvec + 8;                         // 2048
    int*   btot  = (int*)(WcT + NCLASS * NFEAT);     // NBUCK (padded)
    int*   bbase = btot + NBUCK + 1;                 // NBUCK+1 (padded)
    int*   bhist = bbase + NBUCK + 3;                // NBLK*NBUCK
    int*   bbas2 = bhist + (long)NBLK * NBUCK;       // NBLK*NBUCK
    int*   ebufP = bbas2 + (long)NBLK * NBUCK;       // E

    hist_kernel<<<NBLK, 256, 0, stream>>>(edst, bhist, chunk, E);
    scanblk_kernel<<<NBUCK, 256, 0, stream>>>(bhist, bbas2, btot);
    mid_kernel<<<2, 512, 0, stream>>>(btot, bbase, W1, b1, Wfc, bfc, WcT, cvec);
    scat_kernel<<<NBLK, 256, 0, stream>>>(esrc, edst, bbas2, bbase, ebufP, chunk, E);
    deg_dinv_kernel<<<NBUCK, 256, 0, stream>>>(ebufP, bbase, dinv);
    z_kernel<<<1563, 256, 0, stream>>>(x, WcT, dinv, Zs, N);
    sort_gather_kernel<<<NBUCK, 512, 0, stream>>>(Zs, ebufP, bbase, dinv, cvec, out, N);
}

// Round 9
// 238.929 us; speedup vs baseline: 1.3189x; 1.0170x over previous
//
#include <hip/hip_runtime.h>
#include <hip/hip_bf16.h>

#define N_NODES 100000
#define N_EDGES 1600000
#define NFEAT 256
#define NHID 128
#define NCLASS 8

#define NBLK 1024                      // pass-A blocks
#define BSH 8                          // bucket = dst >> 8 (256 nodes/bucket)
#define BUCK 256
#define NBUCK ((N_NODES + BUCK - 1) / BUCK)   // 391
#define CAPE 6144                      // LDS edge capacity (mean 4096, sigma 64)

// ---------------------------------------------------------------------------
// A1: per-block coarse histogram via LDS atomics; int4 edge loads.
__global__ __launch_bounds__(256) void hist_kernel(const int* __restrict__ edst,
                                                   int* __restrict__ blockhist,
                                                   int chunk, int nE) {
    __shared__ int h[NBUCK];
    int tid = threadIdx.x;
    for (int i = tid; i < NBUCK; i += 256) h[i] = 0;
    __syncthreads();
    int e0 = blockIdx.x * chunk;               // chunk is a multiple of 4
    int e1 = min(e0 + chunk, nE);
    for (int e = e0 + tid * 4; e + 3 < e1; e += 1024) {
        int4 d = *(const int4*)&edst[e];
        atomicAdd(&h[d.x >> BSH], 1);
        atomicAdd(&h[d.y >> BSH], 1);
        atomicAdd(&h[d.z >> BSH], 1);
        atomicAdd(&h[d.w >> BSH], 1);
    }
    int full = e0 + ((e1 - e0) & ~3);
    int et = full + tid;
    if (et < e1) atomicAdd(&h[edst[et] >> BSH], 1);
    __syncthreads();
    for (int i = tid; i < NBUCK; i += 256)
        blockhist[(long)blockIdx.x * NBUCK + i] = h[i];
}

// ---------------------------------------------------------------------------
// A2: per-bucket exclusive scan over the 1024 per-block counts (4 rows/thread).
__global__ __launch_bounds__(256) void scanblk_kernel(const int* __restrict__ blockhist,
                                                      int* __restrict__ blockbase,
                                                      int* __restrict__ bucket_total) {
    __shared__ int ss[256];
    int b = blockIdx.x, tid = threadIdx.x;
    int v0 = blockhist[(long)(tid * 4 + 0) * NBUCK + b];
    int v1 = blockhist[(long)(tid * 4 + 1) * NBUCK + b];
    int v2 = blockhist[(long)(tid * 4 + 2) * NBUCK + b];
    int v3 = blockhist[(long)(tid * 4 + 3) * NBUCK + b];
    int t = v0 + v1 + v2 + v3;
    ss[tid] = t; __syncthreads();
    for (int o = 1; o < 256; o <<= 1) {
        int u = (tid >= o) ? ss[tid - o] : 0;
        __syncthreads(); ss[tid] += u; __syncthreads();
    }
    int ex = ss[tid] - t;
    blockbase[(long)(tid * 4 + 0) * NBUCK + b] = ex;
    blockbase[(long)(tid * 4 + 1) * NBUCK + b] = ex + v0;
    blockbase[(long)(tid * 4 + 2) * NBUCK + b] = ex + v0 + v1;
    blockbase[(long)(tid * 4 + 3) * NBUCK + b] = ex + v0 + v1 + v2;
    if (tid == 255) bucket_total[b] = ss[255];
}

// ---------------------------------------------------------------------------
// Mid: block 0 = exclusive scan over bucket totals; block 1 = Wc/cvec precompute.
__global__ __launch_bounds__(512) void mid_kernel(const int* __restrict__ bucket_total,
                                                  int* __restrict__ bucket_base,
                                                  const float* __restrict__ W1,
                                                  const float* __restrict__ b1,
                                                  const float* __restrict__ Wfc,
                                                  const float* __restrict__ bfc,
                                                  float* __restrict__ WcT,
                                                  float* __restrict__ cvec) {
    int tid = threadIdx.x;
    if (blockIdx.x == 0) {
        __shared__ int ss[512];
        int v = (tid < NBUCK) ? bucket_total[tid] : 0;
        ss[tid] = v; __syncthreads();
        for (int o = 1; o < 512; o <<= 1) {
            int u = (tid >= o) ? ss[tid - o] : 0;
            __syncthreads(); ss[tid] += u; __syncthreads();
        }
        if (tid < NBUCK) bucket_base[tid] = ss[tid] - v;
        if (tid == NBUCK - 1) bucket_base[NBUCK] = ss[tid];
    } else {
        __shared__ float wfs[NHID * NCLASS];
        __shared__ float bs[NHID];
        for (int i = tid; i < NHID * NCLASS; i += 512) wfs[i] = Wfc[i];
        if (tid < NHID) bs[tid] = b1[tid];
        __syncthreads();
        if (tid < NFEAT) {
            float acc[NCLASS] = {};
            for (int h = 0; h < NHID; h++) {
                float w = W1[tid * NHID + h];
                #pragma unroll
                for (int c = 0; c < NCLASS; c++) acc[c] += w * wfs[h * NCLASS + c];
            }
            #pragma unroll
            for (int c = 0; c < NCLASS; c++) WcT[c * NFEAT + tid] = acc[c];
        }
        if (tid < NCLASS) {
            float a = bfc[tid];
            for (int h = 0; h < NHID; h++) a += bs[h] * wfs[h * NCLASS + tid];
            cvec[tid] = a;
        }
    }
}

// ---------------------------------------------------------------------------
// A3: scatter packed (src<<8 | local_dst) into bucket-grouped ebufP; int4 loads.
__global__ __launch_bounds__(256) void scat_kernel(const int* __restrict__ esrc,
                                                   const int* __restrict__ edst,
                                                   const int* __restrict__ blockbase,
                                                   const int* __restrict__ bucket_base,
                                                   int* __restrict__ ebufP,
                                                   int chunk, int nE) {
    __shared__ int cur[NBUCK];
    int tid = threadIdx.x;
    for (int i = tid; i < NBUCK; i += 256)
        cur[i] = bucket_base[i] + blockbase[(long)blockIdx.x * NBUCK + i];
    __syncthreads();
    int e0 = blockIdx.x * chunk;
    int e1 = min(e0 + chunk, nE);
    for (int e = e0 + tid * 4; e + 3 < e1; e += 1024) {
        int4 s = *(const int4*)&esrc[e];
        int4 d = *(const int4*)&edst[e];
        int p0 = atomicAdd(&cur[d.x >> BSH], 1);
        int p1 = atomicAdd(&cur[d.y >> BSH], 1);
        int p2 = atomicAdd(&cur[d.z >> BSH], 1);
        int p3 = atomicAdd(&cur[d.w >> BSH], 1);
        ebufP[p0] = (s.x << BSH) | (d.x & (BUCK - 1));
        ebufP[p1] = (s.y << BSH) | (d.y & (BUCK - 1));
        ebufP[p2] = (s.z << BSH) | (d.z & (BUCK - 1));
        ebufP[p3] = (s.w << BSH) | (d.w & (BUCK - 1));
    }
    int full = e0 + ((e1 - e0) & ~3);
    int et = full + tid;
    if (et < e1) {
        int s = esrc[et], d = edst[et];
        int pos = atomicAdd(&cur[d >> BSH], 1);
        ebufP[pos] = (s << BSH) | (d & (BUCK - 1));
    }
}

// ---------------------------------------------------------------------------
// B-lite: exact per-node degree per bucket -> dinv. 512 threads, int4 reads.
__global__ __launch_bounds__(512) void deg_dinv_kernel(const int* __restrict__ ebufP,
                                                       const int* __restrict__ bucket_base,
                                                       float* __restrict__ dinv) {
    __shared__ int cnt[BUCK];
    int b = blockIdx.x, tid = threadIdx.x;
    if (tid < BUCK) cnt[tid] = 0;
    __syncthreads();
    int base = bucket_base[b], end = bucket_base[b + 1];
    int a0 = min((base + 3) & ~3, end);
    if (base + tid < a0) atomicAdd(&cnt[ebufP[base + tid] & (BUCK - 1)], 1);
    for (int e = a0 + tid * 4; e + 3 < end; e += 2048) {
        int4 p = *(const int4*)&ebufP[e];
        atomicAdd(&cnt[p.x & (BUCK - 1)], 1);
        atomicAdd(&cnt[p.y & (BUCK - 1)], 1);
        atomicAdd(&cnt[p.z & (BUCK - 1)], 1);
        atomicAdd(&cnt[p.w & (BUCK - 1)], 1);
    }
    int full = a0 + ((end - a0) & ~3);
    int et = full + tid;
    if (et < end) atomicAdd(&cnt[ebufP[et] & (BUCK - 1)], 1);
    __syncthreads();
    if (tid < BUCK) {
        int node = (b << BSH) + tid;
        if (node < N_NODES) dinv[node] = rsqrtf((float)(cnt[tid] + 1));
    }
}

// ---------------------------------------------------------------------------
// Kz: Zs[i][c] = dot(X[i], WcT[c]) * dinv[i].  Wave = 8 rows; 8 lanes/row
// own 32 features in 8 float4 regs; WcT in LDS; shfl_xor reduce per class.
__global__ __launch_bounds__(256) void z_kernel(const float* __restrict__ X,
                                                const float* __restrict__ WcT,
                                                const float* __restrict__ dinv,
                                                float* __restrict__ Zs, int n) {
    __shared__ float4 wlds[NCLASS * 64];
    int tid = threadIdx.x;
    #pragma unroll
    for (int i = tid; i < NCLASS * 64; i += 256)
        wlds[i] = ((const float4*)WcT)[i];
    __syncthreads();

    const int lane = tid & 63;
    const int sub  = lane & 7;
    const int rsub = lane >> 3;
    const int wid  = (blockIdx.x * 256 + tid) >> 6;
    const int nw   = (gridDim.x * 256) >> 6;
    const int ngroups = (n + 7) >> 3;

    for (int g = wid; g < ngroups; g += nw) {
        int row = g * 8 + rsub;
        bool ok = row < n;
        int r = ok ? row : (n - 1);
        const float4* xr = (const float4*)(X + (long)r * NFEAT);
        float4 xv[8];
        #pragma unroll
        for (int k = 0; k < 8; k++) xv[k] = xr[sub + 8 * k];

        float res = 0.f;
        #pragma unroll
        for (int c = 0; c < NCLASS; c++) {
            float s = 0.f;
            #pragma unroll
            for (int k = 0; k < 8; k++) {
                float4 w = wlds[c * 64 + sub + 8 * k];
                s += xv[k].x * w.x + xv[k].y * w.y + xv[k].z * w.z + xv[k].w * w.w;
            }
            s += __shfl_xor(s, 1);
            s += __shfl_xor(s, 2);
            s += __shfl_xor(s, 4);
            if (sub == c) res = s;
        }
        if (ok) Zs[(long)row * NCLASS + sub] = res * dinv[row];
    }
}

// ---------------------------------------------------------------------------
// Kg: fused in-LDS counting sort + register-accumulate gather.
__global__ __launch_bounds__(512) void sort_gather_kernel(
        const float* __restrict__ Zs,
        const int* __restrict__ ebufP,
        const int* __restrict__ bucket_base,
        const float* __restrict__ cvec,
        float* __restrict__ out, int n) {
    __shared__ int cnt[BUCK];          // counts, then cursors
    __shared__ int off[BUCK + 1];
    __shared__ int ss[BUCK];
    __shared__ int sorted[CAPE];       // fallback reuses as float acc[2048]
    int b = blockIdx.x, tid = threadIdx.x;
    int base = bucket_base[b], end = bucket_base[b + 1];
    int total = end - base;
    const float4* Zs4 = (const float4*)Zs;
    float4 c0v = ((const float4*)cvec)[0];
    float4 c1v = ((const float4*)cvec)[1];

    if (total <= CAPE) {
        if (tid < BUCK) cnt[tid] = 0;
        __syncthreads();
        int a0 = min((base + 3) & ~3, end);
        if (base + tid < a0) atomicAdd(&cnt[ebufP[base + tid] & (BUCK - 1)], 1);
        for (int e = a0 + tid * 4; e + 3 < end; e += 2048) {
            int4 p = *(const int4*)&ebufP[e];
            atomicAdd(&cnt[p.x & (BUCK - 1)], 1);
            atomicAdd(&cnt[p.y & (BUCK - 1)], 1);
            atomicAdd(&cnt[p.z & (BUCK - 1)], 1);
            atomicAdd(&cnt[p.w & (BUCK - 1)], 1);
        }
        int full = a0 + ((end - a0) & ~3);
        if (full + tid < end) atomicAdd(&cnt[ebufP[full + tid] & (BUCK - 1)], 1);
        __syncthreads();

        int t = (tid < BUCK) ? cnt[tid] : 0;
        if (tid < BUCK) ss[tid] = t;
        __syncthreads();
        for (int o = 1; o < BUCK; o <<= 1) {
            int u = 0;
            if (tid < BUCK && tid >= o) u = ss[tid - o];
            __syncthreads();
            if (tid < BUCK) ss[tid] += u;
            __syncthreads();
        }
        if (tid < BUCK) {
            off[tid] = ss[tid] - t;
            cnt[tid] = ss[tid] - t;     // cursor
            if (tid == BUCK - 1) off[BUCK] = ss[tid];
        }
        __syncthreads();

        if (base + tid < a0) {
            int p = ebufP[base + tid];
            int slot = atomicAdd(&cnt[p & (BUCK - 1)], 1);
            sorted[slot] = p >> BSH;
        }
        for (int e = a0 + tid * 4; e + 3 < end; e += 2048) {
            int4 p = *(const int4*)&ebufP[e];
            int s0 = atomicAdd(&cnt[p.x & (BUCK - 1)], 1);
            int s1 = atomicAdd(&cnt[p.y & (BUCK - 1)], 1);
            int s2 = atomicAdd(&cnt[p.z & (BUCK - 1)], 1);
            int s3 = atomicAdd(&cnt[p.w & (BUCK - 1)], 1);
            sorted[s0] = p.x >> BSH;
            sorted[s1] = p.y >> BSH;
            sorted[s2] = p.z >> BSH;
            sorted[s3] = p.w >> BSH;
        }
        if (full + tid < end) {
            int p = ebufP[full + tid];
            int slot = atomicAdd(&cnt[p & (BUCK - 1)], 1);
            sorted[slot] = p >> BSH;
        }
        __syncthreads();

        int li = tid >> 1;
        int h  = tid & 1;
        int node = (b << BSH) + li;
        if (node < n) {
            int k0 = off[li], k1 = off[li + 1];
            float4 a = Zs4[node * 2 + h];                     // self-loop
            int k = k0;
            for (; k + 1 < k1; k += 2) {
                int s0 = sorted[k], s1 = sorted[k + 1];
                float4 z0 = Zs4[s0 * 2 + h];
                float4 z1 = Zs4[s1 * 2 + h];
                a.x += z0.x + z1.x; a.y += z0.y + z1.y;
                a.z += z0.z + z1.z; a.w += z0.w + z1.w;
            }
            if (k < k1) {
                float4 z = Zs4[sorted[k] * 2 + h];
                a.x += z.x; a.y += z.y; a.z += z.z; a.w += z.w;
            }
            float dd = rsqrtf((float)(k1 - k0 + 1));          // local degree
            float4 cv = h ? c1v : c0v;
            float4 o;
            o.x = a.x * dd + cv.x; o.y = a.y * dd + cv.y;
            o.z = a.z * dd + cv.z; o.w = a.w * dd + cv.w;
            ((float4*)out)[node * 2 + h] = o;
        }
    } else {
        // fallback: LDS float-atomic accumulation (never taken in practice)
        float* acc = (float*)sorted;   // 2048 floats
        __shared__ int dcount[BUCK];
        if (tid < BUCK) dcount[tid] = 0;
        for (int i = tid; i < NCLASS * BUCK; i += 512) acc[i] = 0.f;
        __syncthreads();
        for (int e = base + tid; e < end; e += 512) {
            int p = ebufP[e];
            int src = p >> BSH;
            int li = p & (BUCK - 1);
            atomicAdd(&dcount[li], 1);
            float4 z0 = Zs4[src * 2];
            float4 z1 = Zs4[src * 2 + 1];
            atomicAdd(&acc[0 * BUCK + li], z0.x);
            atomicAdd(&acc[1 * BUCK + li], z0.y);
            atomicAdd(&acc[2 * BUCK + li], z0.z);
            atomicAdd(&acc[3 * BUCK + li], z0.w);
            atomicAdd(&acc[4 * BUCK + li], z1.x);
            atomicAdd(&acc[5 * BUCK + li], z1.y);
            atomicAdd(&acc[6 * BUCK + li], z1.z);
            atomicAdd(&acc[7 * BUCK + li], z1.w);
        }
        __syncthreads();
        if (tid < BUCK) {
            int node = (b << BSH) + tid;
            if (node < n) {
                float4 s0 = Zs4[node * 2];
                float4 s1 = Zs4[node * 2 + 1];
                float dd = rsqrtf((float)(dcount[tid] + 1));
                float4 o0, o1;
                o0.x = (s0.x + acc[0 * BUCK + tid]) * dd + c0v.x;
                o0.y = (s0.y + acc[1 * BUCK + tid]) * dd + c0v.y;
                o0.z = (s0.z + acc[2 * BUCK + tid]) * dd + c0v.z;
                o0.w = (s0.w + acc[3 * BUCK + tid]) * dd + c0v.w;
                o1.x = (s1.x + acc[4 * BUCK + tid]) * dd + c1v.x;
                o1.y = (s1.y + acc[5 * BUCK + tid]) * dd + c1v.y;
                o1.z = (s1.z + acc[6 * BUCK + tid]) * dd + c1v.z;
                o1.w = (s1.w + acc[7 * BUCK + tid]) * dd + c1v.w;
                ((float4*)out)[node * 2]     = o0;
                ((float4*)out)[node * 2 + 1] = o1;
            }
        }
    }
}

// ---------------------------------------------------------------------------
extern "C" void kernel_launch(void* const* d_in, const int* in_sizes, int n_in,
                              void* d_out, int out_size, void* d_ws, size_t ws_size,
                              hipStream_t stream) {
    const float* x    = (const float*)d_in[0];   // [N, 256]
    const int*   eidx = (const int*)d_in[1];     // [2, E]
    const float* W1   = (const float*)d_in[2];   // [256, 128]
    const float* b1   = (const float*)d_in[3];   // [128]
    const float* Wfc  = (const float*)d_in[4];   // [128, 8]
    const float* bfc  = (const float*)d_in[5];   // [8]
    float* out = (float*)d_out;

    const int N = N_NODES;
    const int E = in_sizes[1] / 2;
    const int chunk = (((E + NBLK - 1) / NBLK) + 3) & ~3;   // multiple of 4

    const int* esrc = eidx;
    const int* edst = eidx + E;

    // workspace layout (~16 MB); every region written before read, no memsets.
    float* Zs    = (float*)d_ws;                     // 8N   (16B-aligned)
    float* dinv  = Zs + (long)8 * N;                 // N
    float* cvec  = dinv + N;                         // 8    (16B-aligned)
    float* WcT   = cvec + 8;                         // 2048
    int*   btot  = (int*)(WcT + NCLASS * NFEAT);     // NBUCK (padded)
    int*   bbase = btot + NBUCK + 1;                 // NBUCK+1 (padded)
    int*   bhist = bbase + NBUCK + 4;                // NBLK*NBUCK
    int*   bbas2 = bhist + (long)NBLK * NBUCK;       // NBLK*NBUCK
    // 16B-align ebufP for int4 loads
    size_t ofs = (size_t)(bbas2 + (long)NBLK * NBUCK - (int*)d_ws);
    ofs = (ofs + 3) & ~(size_t)3;
    int*   ebufP = (int*)d_ws + ofs;                 // E

    hist_kernel<<<NBLK, 256, 0, stream>>>(edst, bhist, chunk, E);
    scanblk_kernel<<<NBUCK, 256, 0, stream>>>(bhist, bbas2, btot);
    mid_kernel<<<2, 512, 0, stream>>>(btot, bbase, W1, b1, Wfc, bfc, WcT, cvec);
    scat_kernel<<<NBLK, 256, 0, stream>>>(esrc, edst, bbas2, bbase, ebufP, chunk, E);
    deg_dinv_kernel<<<NBUCK, 512, 0, stream>>>(ebufP, bbase, dinv);
    z_kernel<<<1563, 256, 0, stream>>>(x, WcT, dinv, Zs, N);
    sort_gather_kernel<<<NBUCK, 512, 0, stream>>>(Zs, ebufP, bbase, cvec, out, N);
}